// Round 1
// baseline (932.138 us; speedup 1.0000x reference)
//
#include <hip/hip_runtime.h>
#include <cstdint>
#include <climits>
#include <cstddef>

#define TK 13
#define MAXG 128

__device__ __forceinline__ float iou_fn(const float4 pb, const float4 gb){
  float pa = (pb.z - pb.x) * (pb.w - pb.y);
  float ga = (gb.z - gb.x) * (gb.w - gb.y);
  float ltx = fmaxf(pb.x, gb.x), lty = fmaxf(pb.y, gb.y);
  float rbx = fminf(pb.z, gb.z), rby = fminf(pb.w, gb.w);
  float w = fmaxf(rbx - ltx, 0.0f), h = fmaxf(rby - lty, 0.0f);
  float inter = w * h;
  float uni = pa + ga - inter;
  return inter / fmaxf(uni, 1e-6f);
}

__device__ __forceinline__ float sigmoid_f(float x){ return 1.0f / (1.0f + expf(-x)); }

// Must mirror reference: cls_cost + iou_cost + soft_center_prior, INF for invalid priors.
__device__ __forceinline__ float cost_fn(float iou, float s, float px, float py, float stride,
                                         float gcx, float gcy, bool vld){
  if (!vld) return 1e8f;
  float sig = sigmoid_f(s);
  float iouc = -logf(iou + 1e-7f) * 3.0f;
  float scale = iou - sig;
  float bce = fmaxf(s, 0.0f) + log1pf(expf(-fabsf(s))) - s * iou; // logaddexp(0,s) - s*iou
  float cls = bce * scale * scale;
  float dx = px - gcx, dy = py - gcy;
  float dist = sqrtf(dx*dx + dy*dy) / stride;
  float soft = powf(10.0f, dist - 3.0f);
  return cls + iouc + soft;
}

// Kernel A: valid_mask[b,p] = any_g(in_gts && pad); zero fg bytes (ws is poisoned 0xAA).
__global__ __launch_bounds__(256) void k_valid(
    const float4* __restrict__ priors, const float4* __restrict__ gtb,
    const float* __restrict__ pad, uint8_t* __restrict__ valid,
    uint8_t* __restrict__ fgp, int P, int G)
{
  int b = blockIdx.y;
  int p = blockIdx.x * 256 + threadIdx.x;
  __shared__ float4 sg[MAXG];
  __shared__ float sp[MAXG];
  for (int i = threadIdx.x; i < G; i += 256){ sg[i] = gtb[b*G + i]; sp[i] = pad[b*G + i]; }
  __syncthreads();
  if (p >= P) return;
  float4 pr = priors[p];
  bool v = false;
  for (int g = 0; g < G; ++g){
    float4 gb = sg[g];
    bool ig = (pr.x > gb.x) && (pr.y > gb.y) && (gb.z > pr.x) && (gb.w > pr.y);
    v = v || (ig && sp[g] > 0.5f);
  }
  size_t o = (size_t)b * P + p;
  valid[o] = v ? 1 : 0;
  fgp[o] = 0;
}

// Kernel B: one wave per (b,g). One scan over P computing iou/metric/cost; three
// per-lane sorted top-13 lists; shfl-butterfly 64-way merges with exact tie-breaks.
__global__ __launch_bounds__(64) void k_topk(
    const float4* __restrict__ pred_bboxes, const float* __restrict__ pred_scores,
    const float4* __restrict__ priors, const int* __restrict__ gt_labels,
    const float4* __restrict__ gtbb, const float* __restrict__ pad,
    const uint8_t* __restrict__ valid, uint8_t* __restrict__ fgp,
    int* __restrict__ kk, int* __restrict__ msel,
    int P, int G, int C)
{
  int bg = blockIdx.x;
  int b = bg / G;
  int lane = threadIdx.x;
  if (pad[bg] <= 0.5f){ if (lane == 0) kk[bg] = 0; return; }
  float4 gb = gtbb[bg];
  int lbl = gt_labels[bg];
  float gcx = (gb.x + gb.z) * 0.5f, gcy = (gb.y + gb.w) * 0.5f;
  const float FINF = __builtin_inff();

  float mv[TK]; int mi[TK];   // metric top-13 desc, idx packed (p<<1)|in_gts
  float iv[TK];               // iou   top-13 desc (values only)
  float cv[TK]; int ci[TK];   // cost  top-13 asc
  #pragma unroll
  for (int j = 0; j < TK; ++j){ mv[j] = -FINF; mi[j] = INT_MAX; iv[j] = -FINF; cv[j] = FINF; ci[j] = INT_MAX; }

  for (int p = lane; p < P; p += 64){
    float4 pr = priors[p];
    float4 pb = pred_bboxes[(size_t)b*P + p];
    float iou = iou_fn(pb, gb);
    bool ig = (pr.x > gb.x) && (pr.y > gb.y) && (gb.z > pr.x) && (gb.w > pr.y);
    float s = pred_scores[((size_t)b*P + p)*C + lbl];
    float metric = ig ? sigmoid_f(s) * powf(iou, 6.0f) : 0.0f;
    bool vld = valid[(size_t)b*P + p] != 0;
    float cost = cost_fn(iou, s, pr.x, pr.y, pr.z, gcx, gcy, vld);
    { // metric insert (desc, tie -> smaller packed idx == smaller p)
      float v = metric; int ix = (p << 1) | (ig ? 1 : 0);
      if (v > mv[TK-1] || (v == mv[TK-1] && ix < mi[TK-1])){
        #pragma unroll
        for (int j = 0; j < TK; ++j){
          bool bet = (v > mv[j]) || (v == mv[j] && ix < mi[j]);
          if (bet){ float tv = mv[j]; mv[j] = v; v = tv; int ti = mi[j]; mi[j] = ix; ix = ti; }
        }
      }
    }
    { // iou values insert
      float v = iou;
      if (v > iv[TK-1]){
        #pragma unroll
        for (int j = 0; j < TK; ++j){ if (v > iv[j]){ float t = iv[j]; iv[j] = v; v = t; } }
      }
    }
    { // cost insert (asc, tie -> smaller p)
      float v = cost; int ix = p;
      if (v < cv[TK-1] || (v == cv[TK-1] && ix < ci[TK-1])){
        #pragma unroll
        for (int j = 0; j < TK; ++j){
          bool bet = (v < cv[j]) || (v == cv[j] && ix < ci[j]);
          if (bet){ float t = cv[j]; cv[j] = v; v = t; int ti = ci[j]; ci[j] = ix; ix = ti; }
        }
      }
    }
  }

  __shared__ float sv[64 * TK];
  __shared__ int   si[64 * TK];

  // ---- metric merge: 13 winners; mark fg byte for winners with in_gts flag ----
  #pragma unroll
  for (int j = 0; j < TK; ++j){ sv[lane*TK + j] = mv[j]; si[lane*TK + j] = mi[j]; }
  __syncthreads();
  {
    int ptr = 0; float cvv = sv[lane*TK]; int cii = si[lane*TK];
    for (int r = 0; r < TK; ++r){
      float bv = cvv; int bi = cii; int bl = lane;
      #pragma unroll
      for (int off = 32; off >= 1; off >>= 1){
        float ov = __shfl_xor(bv, off); int oi = __shfl_xor(bi, off); int ol = __shfl_xor(bl, off);
        if ((ov > bv) || (ov == bv && oi < bi)){ bv = ov; bi = oi; bl = ol; }
      }
      if (lane == 0 && (bi & 1)) fgp[(size_t)b*P + (bi >> 1)] = 1;
      if (lane == bl){ ptr++; if (ptr < TK){ cvv = sv[lane*TK + ptr]; cii = si[lane*TK + ptr]; } else { cvv = -FINF; cii = INT_MAX; } }
    }
  }
  __syncthreads();

  // ---- iou merge: sum of top-13 in descending order -> dynamic_k ----
  #pragma unroll
  for (int j = 0; j < TK; ++j){ sv[lane*TK + j] = iv[j]; }
  __syncthreads();
  float ksum = 0.0f;
  {
    int ptr = 0; float cvv = sv[lane*TK]; int cii = lane; // lane id as total-order tiebreak
    for (int r = 0; r < TK; ++r){
      float bv = cvv; int bi = cii; int bl = lane;
      #pragma unroll
      for (int off = 32; off >= 1; off >>= 1){
        float ov = __shfl_xor(bv, off); int oi = __shfl_xor(bi, off); int ol = __shfl_xor(bl, off);
        if ((ov > bv) || (ov == bv && oi < bi)){ bv = ov; bi = oi; bl = ol; }
      }
      ksum += bv;
      if (lane == bl){ ptr++; if (ptr < TK){ cvv = sv[lane*TK + ptr]; } else { cvv = -FINF; } }
    }
  }
  int kdyn = (int)ksum; if (kdyn < 1) kdyn = 1;
  __syncthreads();

  // ---- cost merge: 13 smallest-cost prior indices (asc, stable) ----
  #pragma unroll
  for (int j = 0; j < TK; ++j){ sv[lane*TK + j] = cv[j]; si[lane*TK + j] = ci[j]; }
  __syncthreads();
  {
    int ptr = 0; float cvv = sv[lane*TK]; int cii = si[lane*TK];
    for (int r = 0; r < TK; ++r){
      float bv = cvv; int bi = cii; int bl = lane;
      #pragma unroll
      for (int off = 32; off >= 1; off >>= 1){
        float ov = __shfl_xor(bv, off); int oi = __shfl_xor(bi, off); int ol = __shfl_xor(bl, off);
        if ((ov < bv) || (ov == bv && oi < bi)){ bv = ov; bi = oi; bl = ol; }
      }
      if (lane == 0) msel[(size_t)bg*TK + r] = bi;
      if (lane == bl){ ptr++; if (ptr < TK){ cvv = sv[lane*TK + ptr]; cii = si[lane*TK + ptr]; } else { cvv = FINF; cii = INT_MAX; } }
    }
  }
  if (lane == 0) kk[bg] = kdyn;
}

// Kernel C: per (b,p) resolve matching + write all five outputs (as float32).
__global__ __launch_bounds__(256) void k_final(
    const float4* __restrict__ pred_bboxes, const float* __restrict__ pred_scores,
    const float4* __restrict__ priors, const int* __restrict__ gt_labels,
    const float4* __restrict__ gtb, const uint8_t* __restrict__ valid,
    const uint8_t* __restrict__ fgp, const int* __restrict__ kk,
    const int* __restrict__ msel, float* __restrict__ out,
    int B, int P, int G, int C)
{
  int b = blockIdx.y;
  int p = blockIdx.x * 256 + threadIdx.x;
  __shared__ float4 sg[MAXG];
  __shared__ int sl[MAXG];
  __shared__ int sk[MAXG];
  __shared__ int sidx[MAXG * TK];
  for (int i = threadIdx.x; i < G; i += 256){ sg[i] = gtb[b*G + i]; sl[i] = gt_labels[b*G + i]; sk[i] = kk[b*G + i]; }
  for (int i = threadIdx.x; i < G*TK; i += 256){ sidx[i] = msel[(size_t)b*G*TK + i]; }
  __syncthreads();
  if (p >= P) return;
  float4 pb = pred_bboxes[(size_t)b*P + p];
  float4 pr = priors[p];
  int cnt = 0, mg = 0; bool found = false;
  for (int g = 0; g < G; ++g){
    int k = sk[g];
    if (k <= 0) continue;
    bool hit = false;
    #pragma unroll
    for (int j = 0; j < TK; ++j) hit = hit || (j < k && sidx[g*TK + j] == p);
    if (hit){ if (!found){ mg = g; found = true; } cnt++; }
  }
  if (cnt > 1){
    // reference: matching row replaced by onehot of argmin(cost) over ALL g
    bool vld = valid[(size_t)b*P + p] != 0;
    float best = __builtin_inff(); int bgm = 0;
    for (int g = 0; g < G; ++g){
      float4 gb = sg[g];
      float iou = iou_fn(pb, gb);
      float s = pred_scores[((size_t)b*P + p)*C + sl[g]];
      float gcx = (gb.x + gb.z) * 0.5f, gcy = (gb.y + gb.w) * 0.5f;
      float c = cost_fn(iou, s, pr.x, pr.y, pr.z, gcx, gcy, vld);
      if (c < best){ best = c; bgm = g; }
    }
    mg = bgm;
  }
  bool fg = cnt > 0;
  size_t BP = (size_t)B * P;
  size_t o = (size_t)b * P + p;
  out[o] = fg ? (float)sl[mg] : 80.0f;            // assigned_labels (NUM_CLASSES=80)
  out[BP + o] = 1.0f;                             // assigned_labels_weights
  float4 ob = fg ? sg[mg] : make_float4(0.f, 0.f, 0.f, 0.f);
  ((float4*)(out + 2*BP))[o] = ob;                // assigned_bboxes
  out[6*BP + o] = fg ? iou_fn(pb, sg[mg]) : 0.0f; // assign_metrics
  out[7*BP + o] = fgp[o] ? 1.0f : 0.0f;           // fg_mask_pre_prior
}

extern "C" void kernel_launch(void* const* d_in, const int* in_sizes, int n_in,
                              void* d_out, int out_size, void* d_ws, size_t ws_size,
                              hipStream_t stream)
{
  const float4* pred_bboxes = (const float4*)d_in[0];
  const float*  pred_scores = (const float*)d_in[1];
  const float4* priors      = (const float4*)d_in[2];
  const int*    gt_labels   = (const int*)d_in[3];
  const float4* gt_bboxes   = (const float4*)d_in[4];
  const float*  pad         = (const float*)d_in[5];
  int P = in_sizes[2] / 4;                 // 8400
  int B = in_sizes[0] / (P * 4);           // 16
  int C = in_sizes[1] / (B * P);           // 80
  int G = in_sizes[4] / (B * 4);           // 100

  uint8_t* ws = (uint8_t*)d_ws;
  uint8_t* valid = ws;                               // B*P bytes
  uint8_t* fgp   = ws + (size_t)B * P;               // B*P bytes
  int* kk   = (int*)(ws + 2 * (size_t)B * P);        // B*G ints (offset 268800, 16B-aligned)
  int* msel = kk + (size_t)B * G;                    // B*G*13 ints
  float* out = (float*)d_out;

  dim3 gridA((P + 255) / 256, B);
  k_valid<<<gridA, 256, 0, stream>>>(priors, gt_bboxes, pad, valid, fgp, P, G);
  k_topk<<<B * G, 64, 0, stream>>>(pred_bboxes, pred_scores, priors, gt_labels, gt_bboxes, pad,
                                   valid, fgp, kk, msel, P, G, C);
  k_final<<<gridA, 256, 0, stream>>>(pred_bboxes, pred_scores, priors, gt_labels, gt_bboxes,
                                     valid, fgp, kk, msel, out, B, P, G, C);
}

// Round 2
// 813.368 us; speedup vs baseline: 1.1460x; 1.1460x over previous
//
#include <hip/hip_runtime.h>
#include <cstdint>
#include <climits>
#include <cstddef>

#define TK 13
#define MAXG 128

__device__ __forceinline__ float iou_fn(const float4 pb, const float4 gb){
  float pa = (pb.z - pb.x) * (pb.w - pb.y);
  float ga = (gb.z - gb.x) * (gb.w - gb.y);
  float ltx = fmaxf(pb.x, gb.x), lty = fmaxf(pb.y, gb.y);
  float rbx = fminf(pb.z, gb.z), rby = fminf(pb.w, gb.w);
  float w = fmaxf(rbx - ltx, 0.0f), h = fmaxf(rby - lty, 0.0f);
  float inter = w * h;
  float uni = pa + ga - inter;
  return inter / fmaxf(uni, 1e-6f);
}

__device__ __forceinline__ float sigmoid_f(float x){ return 1.0f / (1.0f + expf(-x)); }

// Same expression order as the R0 kernel that passed with absmax 0.
__device__ __forceinline__ float cost_full(float iou, float s, float dist){
  float sig = sigmoid_f(s);
  float iouc = -logf(iou + 1e-7f) * 3.0f;
  float scale = iou - sig;
  float bce = fmaxf(s, 0.0f) + log1pf(expf(-fabsf(s))) - s * iou; // logaddexp(0,s)-s*iou
  float cls = bce * scale * scale;
  float soft = powf(10.0f, dist - 3.0f);
  return cls + iouc + soft;
}

// Kernel A: valid_mask[b,p] = any_g(in_gts && pad); init acc word to 0.
__global__ __launch_bounds__(256) void k_valid(
    const float4* __restrict__ priors, const float4* __restrict__ gtb,
    const float* __restrict__ pad, uint8_t* __restrict__ valid,
    unsigned int* __restrict__ acc, int P, int G)
{
  int b = blockIdx.y;
  int p = blockIdx.x * 256 + threadIdx.x;
  __shared__ float4 sg[MAXG];
  __shared__ float sp[MAXG];
  for (int i = threadIdx.x; i < G; i += 256){ sg[i] = gtb[b*G + i]; sp[i] = pad[b*G + i]; }
  __syncthreads();
  if (p >= P) return;
  float4 pr = priors[p];
  bool v = false;
  for (int g = 0; g < G; ++g){
    float4 gb = sg[g];
    bool ig = (pr.x > gb.x) && (pr.y > gb.y) && (gb.z > pr.x) && (gb.w > pr.y);
    v = v || (ig && sp[g] > 0.5f);
  }
  size_t o = (size_t)b * P + p;
  valid[o] = v ? 1 : 0;
  acc[o] = 0u;
}

// Kernel B: one 4-wave block per (b,g). Pruned scan over P; per-lane top-13
// lists; two-level exact merge; scatter results via atomics into acc.
// acc word: bit1 = fg_pre mark (atomicOr); bits[2..17) = sum of (g<<2) over
// matched selections; bits[17..) = selection count. (sum(g)<=4950 fits 15-2 bits.)
__global__ __launch_bounds__(256) void k_topk(
    const float4* __restrict__ pred_bboxes, const float* __restrict__ pred_scores,
    const float4* __restrict__ priors, const int* __restrict__ gt_labels,
    const float4* __restrict__ gtbb, const float* __restrict__ pad,
    const uint8_t* __restrict__ validb, unsigned int* __restrict__ acc,
    int P, int G, int C)
{
  int bg = blockIdx.x;
  int b = bg / G;
  int g = bg - b * G;
  if (pad[bg] <= 0.5f) return;   // block-uniform exit
  int tid = threadIdx.x;
  int lane = tid & 63;
  int wave = tid >> 6;
  float4 gb = gtbb[bg];
  int lbl = gt_labels[bg];
  float gcx = (gb.x + gb.z) * 0.5f, gcy = (gb.y + gb.w) * 0.5f;
  const float FINF = __builtin_inff();
  size_t bP = (size_t)b * P;

  float mv[TK]; int mi[TK];   // metric top-13 desc, idx packed (p<<1)|in_gts
  float iv[TK];               // iou   top-13 desc (values only)
  float cv[TK]; int ci[TK];   // cost  top-13 asc
  #pragma unroll
  for (int j = 0; j < TK; ++j){ mv[j] = -FINF; mi[j] = INT_MAX; iv[j] = -FINF; cv[j] = FINF; ci[j] = INT_MAX; }
  float thr_d = FINF;  // dist threshold: cost can't enter if dist > thr_d

  for (int p = tid; p < P; p += 256){
    float4 pr = priors[p];
    float4 pb = pred_bboxes[bP + p];
    float iou = iou_fn(pb, gb);
    if (iou > iv[TK-1]){
      float v = iou;
      #pragma unroll
      for (int j = 0; j < TK; ++j){ if (v > iv[j]){ float t = iv[j]; iv[j] = v; v = t; } }
    }
    bool ig = (pr.x > gb.x) && (pr.y > gb.y) && (gb.z > pr.x) && (gb.w > pr.y);
    float i2 = iou * iou;
    float bnd = (i2 * i2 * i2) * 1.000002f;           // >= sigmoid*powf(iou,6)
    bool need_m = ig && !(bnd < mv[TK-1]);
    bool vld = validb[bP + p] != 0;
    float dist = 0.0f; bool need_c = false;
    if (vld){
      float dx = pr.x - gcx, dy = pr.y - gcy;
      dist = sqrtf(dx*dx + dy*dy) / pr.z;
      need_c = !(dist > thr_d);
    }
    float s = 0.0f;
    if (need_m || need_c) s = pred_scores[(bP + p) * C + lbl];
    if (need_m){
      float v = sigmoid_f(s) * powf(iou, 6.0f);
      int ix = (p << 1) | 1;
      if (v > mv[TK-1] || (v == mv[TK-1] && ix < mi[TK-1])){
        #pragma unroll
        for (int j = 0; j < TK; ++j){
          bool bet = (v > mv[j]) || (v == mv[j] && ix < mi[j]);
          if (bet){ float tv = mv[j]; mv[j] = v; v = tv; int ti = mi[j]; mi[j] = ix; ix = ti; }
        }
      }
    } else if (!ig){
      // metric == 0 exactly; competes only on index ties
      float v = 0.0f; int ix = (p << 1);
      if (v > mv[TK-1] || (v == mv[TK-1] && ix < mi[TK-1])){
        #pragma unroll
        for (int j = 0; j < TK; ++j){
          bool bet = (v > mv[j]) || (v == mv[j] && ix < mi[j]);
          if (bet){ float tv = mv[j]; mv[j] = v; v = tv; int ti = mi[j]; mi[j] = ix; ix = ti; }
        }
      }
    }
    if (!vld){
      float v = 1e8f; int ix = p;
      if (v < cv[TK-1] || (v == cv[TK-1] && ix < ci[TK-1])){
        #pragma unroll
        for (int j = 0; j < TK; ++j){
          bool bet = (v < cv[j]) || (v == cv[j] && ix < ci[j]);
          if (bet){ float t = cv[j]; cv[j] = v; v = t; int ti = ci[j]; ci[j] = ix; ix = ti; }
        }
        thr_d = 3.0f + log10f(cv[TK-1] * 1.00002f + 1e-6f);
      }
    } else if (need_c){
      float v = cost_full(iou, s, dist); int ix = p;
      if (v < cv[TK-1] || (v == cv[TK-1] && ix < ci[TK-1])){
        #pragma unroll
        for (int j = 0; j < TK; ++j){
          bool bet = (v < cv[j]) || (v == cv[j] && ix < ci[j]);
          if (bet){ float t = cv[j]; cv[j] = v; v = t; int ti = ci[j]; ci[j] = ix; ix = ti; }
        }
        thr_d = 3.0f + log10f(cv[TK-1] * 1.00002f + 1e-6f);
      }
    }
  }

  // per-thread list slots (each thread reads only its own slots — no barrier needed)
  __shared__ float sv[256 * TK];
  __shared__ int   si[256 * TK];
  __shared__ float swvM[4 * TK]; __shared__ int swiM[4 * TK];
  __shared__ float swvI[4 * TK];
  __shared__ float swvC[4 * TK]; __shared__ int swiC[4 * TK];

  // ---- stage 1: per-wave merges (pointer-advance over 64 sorted lists) ----
  // metric (desc by (v, idx))
  #pragma unroll
  for (int j = 0; j < TK; ++j){ sv[tid*TK + j] = mv[j]; si[tid*TK + j] = mi[j]; }
  {
    int ptr = 0; float cvv = sv[tid*TK]; int cii = si[tid*TK];
    for (int r = 0; r < TK; ++r){
      float bv = cvv; int bi = cii; int bl = lane;
      #pragma unroll
      for (int off = 32; off >= 1; off >>= 1){
        float ov = __shfl_xor(bv, off); int oi = __shfl_xor(bi, off); int ol = __shfl_xor(bl, off);
        if ((ov > bv) || (ov == bv && oi < bi)){ bv = ov; bi = oi; bl = ol; }
      }
      if (lane == 0){ swvM[wave*TK + r] = bv; swiM[wave*TK + r] = bi; }
      if (lane == bl){ ptr++; if (ptr < TK){ cvv = sv[tid*TK + ptr]; cii = si[tid*TK + ptr]; } else { cvv = -FINF; cii = INT_MAX; } }
    }
  }
  // iou (desc by value; lane id as arbitrary total-order tiebreak)
  #pragma unroll
  for (int j = 0; j < TK; ++j){ sv[tid*TK + j] = iv[j]; }
  {
    int ptr = 0; float cvv = sv[tid*TK];
    for (int r = 0; r < TK; ++r){
      float bv = cvv; int bl = lane;
      #pragma unroll
      for (int off = 32; off >= 1; off >>= 1){
        float ov = __shfl_xor(bv, off); int ol = __shfl_xor(bl, off);
        if ((ov > bv) || (ov == bv && ol < bl)){ bv = ov; bl = ol; }
      }
      if (lane == 0){ swvI[wave*TK + r] = bv; }
      if (lane == bl){ ptr++; cvv = (ptr < TK) ? sv[tid*TK + ptr] : -FINF; }
    }
  }
  // cost (asc by (v, idx))
  #pragma unroll
  for (int j = 0; j < TK; ++j){ sv[tid*TK + j] = cv[j]; si[tid*TK + j] = ci[j]; }
  {
    int ptr = 0; float cvv = sv[tid*TK]; int cii = si[tid*TK];
    for (int r = 0; r < TK; ++r){
      float bv = cvv; int bi = cii; int bl = lane;
      #pragma unroll
      for (int off = 32; off >= 1; off >>= 1){
        float ov = __shfl_xor(bv, off); int oi = __shfl_xor(bi, off); int ol = __shfl_xor(bl, off);
        if ((ov < bv) || (ov == bv && oi < bi)){ bv = ov; bi = oi; bl = ol; }
      }
      if (lane == 0){ swvC[wave*TK + r] = bv; swiC[wave*TK + r] = bi; }
      if (lane == bl){ ptr++; if (ptr < TK){ cvv = sv[tid*TK + ptr]; cii = si[tid*TK + ptr]; } else { cvv = FINF; cii = INT_MAX; } }
    }
  }
  __syncthreads();
  if (wave != 0) return;

  // ---- stage 2 (wave 0): select block top-13 from 4x13 candidates ----
  // metric -> fg marks
  {
    float v = (lane < 4*TK) ? swvM[lane] : -FINF;
    int  ii = (lane < 4*TK) ? swiM[lane] : INT_MAX;
    for (int r = 0; r < TK; ++r){
      float bv = v; int bi = ii; int bl = lane;
      #pragma unroll
      for (int off = 32; off >= 1; off >>= 1){
        float ov = __shfl_xor(bv, off); int oi = __shfl_xor(bi, off); int ol = __shfl_xor(bl, off);
        if ((ov > bv) || (ov == bv && oi < bi)){ bv = ov; bi = oi; bl = ol; }
      }
      if (lane == 0 && (bi & 1)) atomicOr(&acc[bP + (bi >> 1)], 2u);
      if (lane == bl){ v = -FINF; ii = INT_MAX; }
    }
  }
  // iou -> dynamic_k (sum of top-13 in desc order, truncate, clamp 1)
  int kdyn;
  {
    float v = (lane < 4*TK) ? swvI[lane] : -FINF;
    float ksum = 0.0f;
    for (int r = 0; r < TK; ++r){
      float bv = v; int bl = lane;
      #pragma unroll
      for (int off = 32; off >= 1; off >>= 1){
        float ov = __shfl_xor(bv, off); int ol = __shfl_xor(bl, off);
        if ((ov > bv) || (ov == bv && ol < bl)){ bv = ov; bl = ol; }
      }
      ksum += bv;
      if (lane == bl){ v = -FINF; }
    }
    kdyn = (int)ksum; if (kdyn < 1) kdyn = 1;
  }
  // cost -> emit first kdyn selections
  {
    float v = (lane < 4*TK) ? swvC[lane] : FINF;
    int  ii = (lane < 4*TK) ? swiC[lane] : INT_MAX;
    for (int r = 0; r < TK; ++r){
      float bv = v; int bi = ii; int bl = lane;
      #pragma unroll
      for (int off = 32; off >= 1; off >>= 1){
        float ov = __shfl_xor(bv, off); int oi = __shfl_xor(bi, off); int ol = __shfl_xor(bl, off);
        if ((ov < bv) || (ov == bv && oi < bi)){ bv = ov; bi = oi; bl = ol; }
      }
      if (lane == 0 && r < kdyn) atomicAdd(&acc[bP + bi], (1u << 17) | ((unsigned)g << 2));
      if (lane == bl){ v = FINF; ii = INT_MAX; }
    }
  }
}

// Kernel C: per (b,p) decode acc; rare multi-match -> argmin-cost recompute; write outputs.
__global__ __launch_bounds__(256) void k_final(
    const float4* __restrict__ pred_bboxes, const float* __restrict__ pred_scores,
    const float4* __restrict__ priors, const int* __restrict__ gt_labels,
    const float4* __restrict__ gtb, const uint8_t* __restrict__ validb,
    const unsigned int* __restrict__ acc, float* __restrict__ out,
    int B, int P, int G, int C)
{
  int b = blockIdx.y;
  int p = blockIdx.x * 256 + threadIdx.x;
  __shared__ float4 sg[MAXG];
  __shared__ int sl[MAXG];
  for (int i = threadIdx.x; i < G; i += 256){ sg[i] = gtb[b*G + i]; sl[i] = gt_labels[b*G + i]; }
  __syncthreads();
  if (p >= P) return;
  size_t o = (size_t)b * P + p;
  unsigned int w = acc[o];
  int cnt = (int)(w >> 17);
  bool fg = cnt > 0;
  int mg = 0;
  float4 pb = pred_bboxes[o];
  if (cnt == 1){
    mg = (int)((w >> 2) & 0x7FFFu);
  } else if (cnt > 1){
    // reference: matching row replaced by onehot of argmin(cost) over ALL g
    float4 pr = priors[p];
    bool vld = validb[o] != 0;
    float best = __builtin_inff();
    for (int gg = 0; gg < G; ++gg){
      float4 gbx = sg[gg];
      float iou = iou_fn(pb, gbx);
      float c;
      if (!vld) c = 1e8f;
      else {
        float s = pred_scores[o * C + sl[gg]];
        float gcx = (gbx.x + gbx.z) * 0.5f, gcy = (gbx.y + gbx.w) * 0.5f;
        float dx = pr.x - gcx, dy = pr.y - gcy;
        float dist = sqrtf(dx*dx + dy*dy) / pr.z;
        c = cost_full(iou, s, dist);
      }
      if (c < best){ best = c; mg = gg; }
    }
  }
  size_t BP = (size_t)B * P;
  out[o] = fg ? (float)sl[mg] : 80.0f;            // assigned_labels (NUM_CLASSES=80)
  out[BP + o] = 1.0f;                             // assigned_labels_weights
  float4 ob = fg ? sg[mg] : make_float4(0.f, 0.f, 0.f, 0.f);
  ((float4*)(out + 2*BP))[o] = ob;                // assigned_bboxes
  out[6*BP + o] = fg ? iou_fn(pb, sg[mg]) : 0.0f; // assign_metrics
  out[7*BP + o] = ((w >> 1) & 1u) ? 1.0f : 0.0f;  // fg_mask_pre_prior
}

extern "C" void kernel_launch(void* const* d_in, const int* in_sizes, int n_in,
                              void* d_out, int out_size, void* d_ws, size_t ws_size,
                              hipStream_t stream)
{
  const float4* pred_bboxes = (const float4*)d_in[0];
  const float*  pred_scores = (const float*)d_in[1];
  const float4* priors      = (const float4*)d_in[2];
  const int*    gt_labels   = (const int*)d_in[3];
  const float4* gt_bboxes   = (const float4*)d_in[4];
  const float*  pad         = (const float*)d_in[5];
  int P = in_sizes[2] / 4;                 // 8400
  int B = in_sizes[0] / (P * 4);           // 16
  int C = in_sizes[1] / (B * P);           // 80
  int G = in_sizes[4] / (B * 4);           // 100

  uint8_t* ws = (uint8_t*)d_ws;
  uint8_t* valid = ws;                                   // B*P bytes
  unsigned int* acc = (unsigned int*)(ws + (size_t)B*P); // B*P uint32 (offset 134400, 4-aligned)
  float* out = (float*)d_out;

  dim3 gridA((P + 255) / 256, B);
  k_valid<<<gridA, 256, 0, stream>>>(priors, gt_bboxes, pad, valid, acc, P, G);
  k_topk<<<B * G, 256, 0, stream>>>(pred_bboxes, pred_scores, priors, gt_labels, gt_bboxes, pad,
                                    valid, acc, P, G, C);
  k_final<<<gridA, 256, 0, stream>>>(pred_bboxes, pred_scores, priors, gt_labels, gt_bboxes,
                                     valid, acc, out, B, P, G, C);
}

// Round 3
// 442.497 us; speedup vs baseline: 2.1065x; 1.8381x over previous
//
#include <hip/hip_runtime.h>
#include <cstdint>
#include <climits>
#include <cstddef>

#define TK 13
#define MAXG 128

__device__ __forceinline__ float iou_fn(const float4 pb, const float4 gb){
  float pa = (pb.z - pb.x) * (pb.w - pb.y);
  float ga = (gb.z - gb.x) * (gb.w - gb.y);
  float ltx = fmaxf(pb.x, gb.x), lty = fmaxf(pb.y, gb.y);
  float rbx = fminf(pb.z, gb.z), rby = fminf(pb.w, gb.w);
  float w = fmaxf(rbx - ltx, 0.0f), h = fmaxf(rby - lty, 0.0f);
  float inter = w * h;
  float uni = pa + ga - inter;
  return inter / fmaxf(uni, 1e-6f);
}

__device__ __forceinline__ float sigmoid_f(float x){ return 1.0f / (1.0f + expf(-x)); }

// Same expression order as R0-R2 (passed absmax 0) — do not alter.
__device__ __forceinline__ float cost_full(float iou, float s, float dist){
  float sig = sigmoid_f(s);
  float iouc = -logf(iou + 1e-7f) * 3.0f;
  float scale = iou - sig;
  float bce = fmaxf(s, 0.0f) + log1pf(expf(-fabsf(s))) - s * iou;
  float cls = bce * scale * scale;
  float soft = powf(10.0f, dist - 3.0f);
  return cls + iouc + soft;
}

// descending u64 sorted-insert, list[0] largest; sentinel 0
__device__ __forceinline__ void ins13(unsigned long long* a, unsigned long long k){
  if (k <= a[TK-1]) return;
  #pragma unroll
  for (int j = 0; j < TK; ++j){
    if (k > a[j]){ unsigned long long t = a[j]; a[j] = k; k = t; }
  }
}

// Kernel A: valid_mask + acc init.
__global__ __launch_bounds__(256) void k_valid(
    const float4* __restrict__ priors, const float4* __restrict__ gtb,
    const float* __restrict__ pad, uint8_t* __restrict__ valid,
    unsigned int* __restrict__ acc, int P, int G)
{
  int b = blockIdx.y;
  int p = blockIdx.x * 256 + threadIdx.x;
  __shared__ float4 sg[MAXG];
  __shared__ float sp[MAXG];
  for (int i = threadIdx.x; i < G; i += 256){ sg[i] = gtb[b*G + i]; sp[i] = pad[b*G + i]; }
  __syncthreads();
  if (p >= P) return;
  float4 pr = priors[p];
  bool v = false;
  for (int g = 0; g < G; ++g){
    float4 gb = sg[g];
    bool ig = (pr.x > gb.x) && (pr.y > gb.y) && (gb.z > pr.x) && (gb.w > pr.y);
    v = v || (ig && sp[g] > 0.5f);
  }
  size_t o = (size_t)b * P + p;
  valid[o] = v ? 1 : 0;
  acc[o] = 0u;
}

// wave0-only: merge 128 sorted desc u64 lists (13 each) in LDS; extract top-13.
// Round-r winner left in lane r's *win. Keys are unique (index in low bits).
__device__ __forceinline__ void merge13_win(const unsigned long long* L, int lane,
                                            unsigned long long* win){
  unsigned long long h0 = L[(2*lane)*TK];
  unsigned long long h1 = L[(2*lane+1)*TK];
  int p0 = 0, p1 = 0;
  unsigned long long w = 0;
  for (int r = 0; r < TK; ++r){
    unsigned long long m = h0 > h1 ? h0 : h1;
    #pragma unroll
    for (int off = 32; off >= 1; off >>= 1){
      unsigned long long o = __shfl_xor(m, off);
      if (o > m) m = o;
    }
    if (lane == r) w = m;
    if (m == h0){ p0++; h0 = (p0 < TK) ? L[(2*lane)*TK + p0] : 0ull; }
    else if (m == h1){ p1++; h1 = (p1 < TK) ? L[(2*lane+1)*TK + p1] : 0ull; }
  }
  *win = w;
}

__device__ __forceinline__ float merge13_sum(const unsigned long long* L, int lane){
  unsigned long long h0 = L[(2*lane)*TK];
  unsigned long long h1 = L[(2*lane+1)*TK];
  int p0 = 0, p1 = 0;
  float ks = 0.0f;
  for (int r = 0; r < TK; ++r){
    unsigned long long m = h0 > h1 ? h0 : h1;
    #pragma unroll
    for (int off = 32; off >= 1; off >>= 1){
      unsigned long long o = __shfl_xor(m, off);
      if (o > m) m = o;
    }
    ks += __uint_as_float((unsigned)(m >> 32));   // descending-order sum (fp-exact vs ref)
    if (m == h0){ p0++; h0 = (p0 < TK) ? L[(2*lane)*TK + p0] : 0ull; }
    else if (m == h1){ p1++; h1 = (p1 < TK) ? L[(2*lane+1)*TK + p1] : 0ull; }
  }
  return ks;
}

// Kernel B: one 2-wave block per (b,g). Pruned scan (block-shared thresholds),
// u64-key per-lane top-13 lists, single 13-round exact merge per criterion.
__global__ __launch_bounds__(128) void k_topk(
    const float4* __restrict__ pred_bboxes, const float* __restrict__ pred_scores,
    const float4* __restrict__ priors, const int* __restrict__ gt_labels,
    const float4* __restrict__ gtbb, const float* __restrict__ pad,
    const uint8_t* __restrict__ validb, unsigned int* __restrict__ acc,
    int P, int G, int C)
{
  int bg = blockIdx.x;
  int b = bg / G;
  int g = bg - b * G;
  if (pad[bg] <= 0.5f) return;   // block-uniform exit
  int tid = threadIdx.x;
  float4 gb = gtbb[bg];
  int lbl = gt_labels[bg];
  float gcx = (gb.x + gb.z) * 0.5f, gcy = (gb.y + gb.w) * 0.5f;
  size_t bP = (size_t)b * P;

  __shared__ unsigned long long slist[128 * TK];   // 13.3 KB, reused for all 3 merges
  __shared__ unsigned int shw[2];                  // [0]=cost-13th bits (min), [1]=metric-13th bits (max)
  if (tid == 0){ shw[0] = __float_as_uint(1e38f); shw[1] = 0u; }
  __syncthreads();

  unsigned long long ml[TK];   // metric keys desc: (bits(v)<<32) | ~((p<<1)|ig)
  unsigned long long cl[TK];   // cost keys, stored bit-inverted so "max" = min (cost,p)
  float ivl[TK];               // iou values desc
  #pragma unroll
  for (int j = 0; j < TK; ++j){ ml[j] = 0ull; cl[j] = 0ull; ivl[j] = -1.0f; }

  unsigned cmLast = 0u;  float thr = 1e30f;
  for (int p = tid; p < P; p += 128){
    float4 pr = priors[p];
    float4 pb = pred_bboxes[bP + p];
    float iou = iou_fn(pb, gb);
    if (iou > ivl[TK-1]){
      float v = iou;
      #pragma unroll
      for (int j = 0; j < TK; ++j){ if (v > ivl[j]){ float t = ivl[j]; ivl[j] = v; v = t; } }
    }
    bool ig = (pr.x > gb.x) && (pr.y > gb.y) && (gb.z > pr.x) && (gb.w > pr.y);
    // refresh shared thresholds (LDS broadcast reads)
    unsigned cm = shw[0];
    if (cm != cmLast){ cmLast = cm; thr = 3.0f + log10f(__uint_as_float(cm) * 1.00002f + 1e-6f); }
    float mB = __uint_as_float(shw[1]);
    float i2 = iou * iou;
    float bnd = (i2 * i2) * i2 * 1.000002f;        // >= sigmoid*powf(iou,6)
    bool need_m = ig && !(bnd < mB);
    bool vld = validb[bP + p] != 0;
    float dist = 0.0f; bool need_c = false;
    if (vld){
      float dx = pr.x - gcx, dy = pr.y - gcy;
      dist = sqrtf(dx*dx + dy*dy) / pr.z;
      need_c = !(dist > thr);
    }
    float s = 0.0f;
    if (need_m || need_c) s = pred_scores[(bP + p) * C + lbl];
    if (need_m){
      float met = sigmoid_f(s) * powf(iou, 6.0f);
      unsigned long long k = ((unsigned long long)__float_as_uint(met) << 32)
                           | (unsigned)~(unsigned)((p << 1) | 1);
      ins13(ml, k);
      unsigned m13 = (unsigned)(ml[TK-1] >> 32);
      if (ml[TK-1] != 0ull && __uint_as_float(m13) > mB) atomicMax(&shw[1], m13);
    } else if (!ig){
      ins13(ml, (unsigned long long)(unsigned)~(unsigned)(p << 1));  // metric==0, index tie
    }
    if (!vld || need_c){
      float c = vld ? cost_full(iou, s, dist) : 1e8f;
      unsigned long long k = ~(((unsigned long long)__float_as_uint(c) << 32) | (unsigned)p);
      if (k > cl[TK-1]){
        ins13(cl, k);
        if (cl[TK-1] != 0ull){
          unsigned cb = (unsigned)((~cl[TK-1]) >> 32);
          if (cb < cmLast || cmLast == 0u) atomicMin(&shw[0], cb);
        }
      }
    }
  }

  int lane = tid;  // valid for wave0 (tid<64)
  // ---- metric: dump, merge, mark fg ----
  #pragma unroll
  for (int j = 0; j < TK; ++j) slist[tid*TK + j] = ml[j];
  __syncthreads();
  if (tid < 64){
    unsigned long long mwin;
    merge13_win(slist, lane, &mwin);
    if (lane < TK && mwin != 0ull){
      unsigned ix = ~(unsigned)(mwin & 0xFFFFFFFFull);
      if (ix & 1u) atomicOr(&acc[bP + (ix >> 1)], 2u);
    }
  }
  __syncthreads();
  // ---- iou: dump as keys, merge, dynamic_k ----
  #pragma unroll
  for (int j = 0; j < TK; ++j)
    slist[tid*TK + j] = ((unsigned long long)__float_as_uint(ivl[j] > 0.0f ? ivl[j] : 0.0f) << 32)
                      | (unsigned)(tid*TK + j + 1);
  __syncthreads();
  __shared__ int skdyn;
  if (tid < 64){
    float ks = merge13_sum(slist, lane);
    int kd = (int)ks; if (kd < 1) kd = 1;
    if (lane == 0) skdyn = kd;
  }
  __syncthreads();
  // ---- cost: dump, merge, emit first kdyn selections ----
  #pragma unroll
  for (int j = 0; j < TK; ++j) slist[tid*TK + j] = cl[j];
  __syncthreads();
  if (tid < 64){
    unsigned long long cwin;
    merge13_win(slist, lane, &cwin);
    int kd = skdyn;
    if (lane < kd && cwin != 0ull){
      unsigned long long key = ~cwin;
      unsigned p = (unsigned)(key & 0xFFFFFFFFull);
      atomicAdd(&acc[bP + p], (1u << 17) | ((unsigned)g << 2));
    }
  }
}

// Kernel C: per (b,p) decode acc; multi-match -> dist-pruned argmin-cost; write outputs.
__global__ __launch_bounds__(256) void k_final(
    const float4* __restrict__ pred_bboxes, const float* __restrict__ pred_scores,
    const float4* __restrict__ priors, const int* __restrict__ gt_labels,
    const float4* __restrict__ gtb, const uint8_t* __restrict__ validb,
    const unsigned int* __restrict__ acc, float* __restrict__ out,
    int B, int P, int G, int C)
{
  int b = blockIdx.y;
  int p = blockIdx.x * 256 + threadIdx.x;
  __shared__ float4 sg[MAXG];
  __shared__ int sl[MAXG];
  __shared__ float2 sc[MAXG];
  for (int i = threadIdx.x; i < G; i += 256){
    float4 gbx = gtb[b*G + i];
    sg[i] = gbx; sl[i] = gt_labels[b*G + i];
    sc[i] = make_float2((gbx.x + gbx.z) * 0.5f, (gbx.y + gbx.w) * 0.5f);
  }
  __syncthreads();
  if (p >= P) return;
  size_t o = (size_t)b * P + p;
  unsigned int w = acc[o];
  int cnt = (int)(w >> 17);
  bool fg = cnt > 0;
  int mg = 0;
  float4 pb = pred_bboxes[o];
  if (cnt == 1){
    mg = (int)((w >> 2) & 0x7FFFu);
  } else if (cnt > 1){
    bool vld = validb[o] != 0;
    if (vld){
      float4 pr = priors[p];
      // pass 1: min-dist gt (first-min tie), seed best with its exact cost
      float bd = __builtin_inff(); int gd = 0;
      for (int gg = 0; gg < G; ++gg){
        float dx = pr.x - sc[gg].x, dy = pr.y - sc[gg].y;
        float d = sqrtf(dx*dx + dy*dy) / pr.z;
        if (d < bd){ bd = d; gd = gg; }
      }
      float s0 = pred_scores[o * C + sl[gd]];
      float bestc = cost_full(iou_fn(pb, sg[gd]), s0, bd);
      mg = gd;
      // pass 2: exact argmin with safe soft-center lower-bound pruning
      for (int gg = 0; gg < G; ++gg){
        float dx = pr.x - sc[gg].x, dy = pr.y - sc[gg].y;
        float d = sqrtf(dx*dx + dy*dy) / pr.z;
        float lb = exp2f((d - 3.0f) * 3.321928f) * 0.9999f - 1e-6f; // <= powf(10,d-3), cost >= lb
        if (lb > bestc) continue;
        float s = pred_scores[o * C + sl[gg]];
        float c = cost_full(iou_fn(pb, sg[gg]), s, d);
        if (c < bestc || (c == bestc && gg < mg)){ bestc = c; mg = gg; }
      }
    } else {
      mg = 0;  // all costs equal 1e8 -> argmin = 0
    }
  }
  size_t BP = (size_t)B * P;
  out[o] = fg ? (float)sl[mg] : 80.0f;            // assigned_labels
  out[BP + o] = 1.0f;                             // assigned_labels_weights
  float4 ob = fg ? sg[mg] : make_float4(0.f, 0.f, 0.f, 0.f);
  ((float4*)(out + 2*BP))[o] = ob;                // assigned_bboxes
  out[6*BP + o] = fg ? iou_fn(pb, sg[mg]) : 0.0f; // assign_metrics
  out[7*BP + o] = ((w >> 1) & 1u) ? 1.0f : 0.0f;  // fg_mask_pre_prior
}

extern "C" void kernel_launch(void* const* d_in, const int* in_sizes, int n_in,
                              void* d_out, int out_size, void* d_ws, size_t ws_size,
                              hipStream_t stream)
{
  const float4* pred_bboxes = (const float4*)d_in[0];
  const float*  pred_scores = (const float*)d_in[1];
  const float4* priors      = (const float4*)d_in[2];
  const int*    gt_labels   = (const int*)d_in[3];
  const float4* gt_bboxes   = (const float4*)d_in[4];
  const float*  pad         = (const float*)d_in[5];
  int P = in_sizes[2] / 4;                 // 8400
  int B = in_sizes[0] / (P * 4);           // 16
  int C = in_sizes[1] / (B * P);           // 80
  int G = in_sizes[4] / (B * 4);           // 100

  uint8_t* ws = (uint8_t*)d_ws;
  uint8_t* valid = ws;                                   // B*P bytes
  unsigned int* acc = (unsigned int*)(ws + (size_t)B*P); // B*P uint32
  float* out = (float*)d_out;

  dim3 gridA((P + 255) / 256, B);
  k_valid<<<gridA, 256, 0, stream>>>(priors, gt_bboxes, pad, valid, acc, P, G);
  k_topk<<<B * G, 128, 0, stream>>>(pred_bboxes, pred_scores, priors, gt_labels, gt_bboxes, pad,
                                    valid, acc, P, G, C);
  k_final<<<gridA, 256, 0, stream>>>(pred_bboxes, pred_scores, priors, gt_labels, gt_bboxes,
                                     valid, acc, out, B, P, G, C);
}